// Round 4
// baseline (4784.999 us; speedup 1.0000x reference)
//
#include <hip/hip_runtime.h>
#include <math.h>

#define LNUM 4
#define H 12
#define D 768
#define DH 64
#define FFD 3072
#define S 512
#define NSEQ 5
#define NT (NSEQ*S)
#define E_N 100
#define M_N 300
#define T_N 900
#define P_N 400
#define EPAD 120
#define NPIX (EPAD*EPAD)
#define C1 256

// ---------------- reduction helpers (blockDim == 256) ----------------
__device__ __forceinline__ float warp_reduce_sum(float v) {
#pragma unroll
  for (int off = 32; off > 0; off >>= 1) v += __shfl_down(v, off, 64);
  return v;
}
__device__ __forceinline__ float warp_reduce_max(float v) {
#pragma unroll
  for (int off = 32; off > 0; off >>= 1) v = fmaxf(v, __shfl_down(v, off, 64));
  return v;
}
__device__ __forceinline__ float block_sum(float v, float* sb) {
  v = warp_reduce_sum(v);
  __syncthreads();
  if ((threadIdx.x & 63) == 0) sb[threadIdx.x >> 6] = v;
  __syncthreads();
  if (threadIdx.x == 0) sb[0] = sb[0] + sb[1] + sb[2] + sb[3];
  __syncthreads();
  return sb[0];
}

// ---------------- embedding + LN ----------------
__global__ __launch_bounds__(256) void embed_ln_kernel(
    const int* __restrict__ ids, const float* __restrict__ emb,
    const float* __restrict__ pos, const float* __restrict__ g,
    const float* __restrict__ b, float* __restrict__ x) {
  __shared__ float sv[D];
  __shared__ float sb[4];
  int t = blockIdx.x;
  int s = t % S;
  int id = ids[t];
  float lsum = 0.f;
  for (int d = threadIdx.x; d < D; d += 256) {
    float val = emb[(size_t)id * D + d] + pos[(size_t)s * D + d];
    sv[d] = val;
    lsum += val;
  }
  float mean = block_sum(lsum, sb) * (1.f / D);
  float lvar = 0.f;
  for (int d = threadIdx.x; d < D; d += 256) {
    float c = sv[d] - mean;
    lvar += c * c;
  }
  float var = block_sum(lvar, sb) * (1.f / D);
  float rstd = rsqrtf(var + 1e-12f);
  for (int d = threadIdx.x; d < D; d += 256)
    x[(size_t)t * D + d] = (sv[d] - mean) * rstd * g[d] + b[d];
}

// ---------------- x = LN(x + tmp) ----------------
__global__ __launch_bounds__(256) void add_ln_kernel(
    float* __restrict__ x, const float* __restrict__ tmp,
    const float* __restrict__ g, const float* __restrict__ b) {
  __shared__ float sv[D];
  __shared__ float sb[4];
  int t = blockIdx.x;
  float lsum = 0.f;
  for (int d = threadIdx.x; d < D; d += 256) {
    float v = x[(size_t)t * D + d] + tmp[(size_t)t * D + d];
    sv[d] = v;
    lsum += v;
  }
  float mean = block_sum(lsum, sb) * (1.f / D);
  float lvar = 0.f;
  for (int d = threadIdx.x; d < D; d += 256) {
    float c = sv[d] - mean;
    lvar += c * c;
  }
  float rstd = rsqrtf(block_sum(lvar, sb) * (1.f / D) + 1e-12f);
  for (int d = threadIdx.x; d < D; d += 256)
    x[(size_t)t * D + d] = (sv[d] - mean) * rstd * g[d] + b[d];
}

// ---------------- generic fp32 tiled GEMM: C = act(A@B + bias) ----------------
// A (Md,Kd) lda, B (Kd,Nd) ldb row-major. act: 0 none, 1 gelu(tanh)
__global__ __launch_bounds__(256) void gemm_f32(
    const float* __restrict__ A, int lda, const float* __restrict__ B, int ldb,
    float* __restrict__ C, int ldc, int Md, int Nd, int Kd,
    const float* __restrict__ bias, int act) {
  __shared__ float As[16][68];
  __shared__ float Bs[16][68];
  int tid = threadIdx.x;
  int tx = tid & 15, ty = tid >> 4;
  int row0 = blockIdx.y * 64, col0 = blockIdx.x * 64;
  int ar = tid >> 2, ak = (tid & 3) * 4;
  int br = tid >> 4, bc = (tid & 15) * 4;
  float acc[4][4] = {};
  for (int k0 = 0; k0 < Kd; k0 += 16) {
    float4 av = make_float4(0.f, 0.f, 0.f, 0.f);
    if (row0 + ar < Md)
      av = *(const float4*)(A + (size_t)(row0 + ar) * lda + k0 + ak);
    float4 bv = make_float4(0.f, 0.f, 0.f, 0.f);
    if (col0 + bc < Nd)
      bv = *(const float4*)(B + (size_t)(k0 + br) * ldb + col0 + bc);
    As[ak + 0][ar] = av.x;
    As[ak + 1][ar] = av.y;
    As[ak + 2][ar] = av.z;
    As[ak + 3][ar] = av.w;
    *(float4*)&Bs[br][bc] = bv;
    __syncthreads();
#pragma unroll
    for (int kk = 0; kk < 16; ++kk) {
      float4 a4 = *(const float4*)&As[kk][ty * 4];
      float4 b4 = *(const float4*)&Bs[kk][tx * 4];
      float aa[4] = {a4.x, a4.y, a4.z, a4.w};
      float bb[4] = {b4.x, b4.y, b4.z, b4.w};
#pragma unroll
      for (int m = 0; m < 4; ++m)
#pragma unroll
        for (int n = 0; n < 4; ++n) acc[m][n] += aa[m] * bb[n];
    }
    __syncthreads();
  }
#pragma unroll
  for (int m = 0; m < 4; ++m) {
    int r = row0 + ty * 4 + m;
    if (r >= Md) continue;
#pragma unroll
    for (int n = 0; n < 4; ++n) {
      int c = col0 + tx * 4 + n;
      if (c >= Nd) continue;
      float v = acc[m][n];
      if (bias) v += bias[c];
      if (act == 1) {
        float x3 = v * v * v;
        v = 0.5f * v * (1.f + tanhf(0.79788456080286535588f * (v + 0.044715f * x3)));
      }
      C[(size_t)r * ldc + c] = v;
    }
  }
}

// ---------------- attention: scores for one sequence b ----------------
// sc[h,i,j] = (q_b,i,h . k_b,j,h)/8 + (1-mask[b,j])*-1e9
__global__ __launch_bounds__(256) void attn_scores_kernel(
    const float* __restrict__ q, const float* __restrict__ k,
    const float* __restrict__ mask, float* __restrict__ sc, int b) {
  __shared__ float As[64][68];
  __shared__ float Bs[64][68];
  int tid = threadIdx.x;
  int tx = tid & 15, ty = tid >> 4;
  int h = blockIdx.z;
  int i0 = blockIdx.y * 64, j0 = blockIdx.x * 64;
  const float* qb = q + (size_t)b * S * D + h * DH;
  const float* kb = k + (size_t)b * S * D + h * DH;
  int lr = tid >> 2, lc = (tid & 3) * 16;
#pragma unroll
  for (int c = 0; c < 4; ++c) {
    float4 av = *(const float4*)(qb + (size_t)(i0 + lr) * D + lc + c * 4);
    As[lc + c * 4 + 0][lr] = av.x;
    As[lc + c * 4 + 1][lr] = av.y;
    As[lc + c * 4 + 2][lr] = av.z;
    As[lc + c * 4 + 3][lr] = av.w;
    float4 bv = *(const float4*)(kb + (size_t)(j0 + lr) * D + lc + c * 4);
    Bs[lc + c * 4 + 0][lr] = bv.x;
    Bs[lc + c * 4 + 1][lr] = bv.y;
    Bs[lc + c * 4 + 2][lr] = bv.z;
    Bs[lc + c * 4 + 3][lr] = bv.w;
  }
  __syncthreads();
  float acc[4][4] = {};
#pragma unroll
  for (int kk = 0; kk < 64; ++kk) {
    float4 a4 = *(const float4*)&As[kk][ty * 4];
    float4 b4 = *(const float4*)&Bs[kk][tx * 4];
    float aa[4] = {a4.x, a4.y, a4.z, a4.w};
    float bb[4] = {b4.x, b4.y, b4.z, b4.w};
#pragma unroll
    for (int m = 0; m < 4; ++m)
#pragma unroll
      for (int n = 0; n < 4; ++n) acc[m][n] += aa[m] * bb[n];
  }
  float* outp = sc + ((size_t)h * S + i0) * S + j0;
#pragma unroll
  for (int n = 0; n < 4; ++n) {
    int j = j0 + tx * 4 + n;
    float bb = (1.f - mask[(size_t)b * S + j]) * -1e9f;
#pragma unroll
    for (int m = 0; m < 4; ++m)
      outp[(size_t)(ty * 4 + m) * S + tx * 4 + n] = acc[m][n] * 0.125f + bb;
  }
}

// ---------------- softmax over last dim (rows of length S) ----------------
__global__ __launch_bounds__(256) void softmax_kernel(float* __restrict__ sc) {
  __shared__ float sb[4];
  float* p = sc + (size_t)blockIdx.x * S;
  int tid = threadIdx.x;
  float v0 = p[tid], v1 = p[tid + 256];
  float mx = warp_reduce_max(fmaxf(v0, v1));
  __syncthreads();
  if ((tid & 63) == 0) sb[tid >> 6] = mx;
  __syncthreads();
  float bm = fmaxf(fmaxf(sb[0], sb[1]), fmaxf(sb[2], sb[3]));
  float e0 = expf(v0 - bm), e1 = expf(v1 - bm);
  float s = block_sum(e0 + e1, sb);
  float inv = 1.f / s;
  p[tid] = e0 * inv;
  p[tid + 256] = e1 * inv;
}

// ---------------- ctx[b,i,h,:] = sum_j a[h,i,j] v[b,j,h,:] ----------------
__global__ __launch_bounds__(256) void attn_ctx_kernel(
    const float* __restrict__ a, const float* __restrict__ v,
    float* __restrict__ ctx, int b) {
  __shared__ float As[16][68];
  __shared__ float Bs[16][68];
  int tid = threadIdx.x;
  int tx = tid & 15, ty = tid >> 4;
  int h = blockIdx.z;
  int i0 = blockIdx.y * 64;
  const float* ab = a + ((size_t)h * S + i0) * S;
  const float* vb = v + (size_t)b * S * D + h * DH;
  int ar = tid >> 2, ak = (tid & 3) * 4;
  int br = tid >> 4, bc = (tid & 15) * 4;
  float acc[4][4] = {};
  for (int k0 = 0; k0 < S; k0 += 16) {
    float4 av = *(const float4*)(ab + (size_t)ar * S + k0 + ak);
    float4 bv = *(const float4*)(vb + (size_t)(k0 + br) * D + bc);
    As[ak + 0][ar] = av.x;
    As[ak + 1][ar] = av.y;
    As[ak + 2][ar] = av.z;
    As[ak + 3][ar] = av.w;
    *(float4*)&Bs[br][bc] = bv;
    __syncthreads();
#pragma unroll
    for (int kk = 0; kk < 16; ++kk) {
      float4 a4 = *(const float4*)&As[kk][ty * 4];
      float4 b4 = *(const float4*)&Bs[kk][tx * 4];
      float aa[4] = {a4.x, a4.y, a4.z, a4.w};
      float bb[4] = {b4.x, b4.y, b4.z, b4.w};
#pragma unroll
      for (int m = 0; m < 4; ++m)
#pragma unroll
        for (int n = 0; n < 4; ++n) acc[m][n] += aa[m] * bb[n];
    }
    __syncthreads();
  }
  float* outp = ctx + ((size_t)b * S + i0) * D + h * DH;
#pragma unroll
  for (int m = 0; m < 4; ++m)
#pragma unroll
    for (int n = 0; n < 4; ++n)
      outp[(size_t)(ty * 4 + m) * D + tx * 4 + n] = acc[m][n];
}

// ---------------- segment ops ----------------
__global__ void seg_mention_kernel(const float* __restrict__ x,
                                   const int* __restrict__ span_idx,
                                   const int* __restrict__ mids,
                                   float* m_sum, float* m_cnt) {
  int t = blockIdx.x;
  int tok = span_idx[t];
  int m = mids[t];
  for (int d = threadIdx.x; d < D; d += 256)
    atomicAdd(&m_sum[(size_t)m * D + d], x[(size_t)tok * D + d]);
  if (threadIdx.x == 0) atomicAdd(&m_cnt[m], 1.f);
}

__global__ void m_div_kernel(float* m_sum, const float* m_cnt) {
  int i = blockIdx.x * 256 + threadIdx.x;
  if (i < M_N * D) m_sum[i] /= m_cnt[i / D];
}

__global__ void seg_entity_kernel(const float* __restrict__ m_emb,
                                  const int* __restrict__ eom, float* e_sum,
                                  float* e_cnt, int* last_m) {
  int m = blockIdx.x;
  int e = eom[m];
  for (int d = threadIdx.x; d < D; d += 256)
    atomicAdd(&e_sum[(size_t)e * D + d], m_emb[(size_t)m * D + d]);
  if (threadIdx.x == 0) {
    atomicAdd(&e_cnt[e], 1.f);
    atomicMax(&last_m[e], m);
  }
}

__global__ void ent_make_kernel(const float* e_sum, const float* e_cnt,
                                const int* last_m, const float* m_emb,
                                float* ent, float* ep) {
  int e = blockIdx.x;
  int lm = last_m[e];
  float inv = 1.f / e_cnt[e];
  for (int d = threadIdx.x; d < D; d += 256) {
    float v = (e_sum[(size_t)e * D + d] + m_emb[(size_t)lm * D + d]) * inv;
    ent[(size_t)e * D + d] = v;
    ep[(size_t)e * D + d] = v;
  }
}

__global__ __launch_bounds__(256) void row_norms_kernel(const float* ep, float* norms) {
  __shared__ float sb[4];
  int r = blockIdx.x;
  float s = 0.f;
  for (int d = threadIdx.x; d < D; d += 256) {
    float v = ep[(size_t)r * D + d];
    s += v * v;
  }
  s = block_sum(s, sb);
  if (threadIdx.x == 0) norms[r] = sqrtf(s);
}

// ---------------- pairwise maps: dot / cos / bil ----------------
__global__ __launch_bounds__(256) void pair_maps_kernel(
    const float* __restrict__ ep, const float* __restrict__ epw,
    const float* __restrict__ norms, const float* __restrict__ b_bil,
    float* __restrict__ attn_in) {
  int wv = threadIdx.x >> 6, lane = threadIdx.x & 63;
  int pi = blockIdx.x * 4 + wv;
  int i = pi / EPAD, j = pi % EPAD;
  float dot = 0.f, bil = 0.f;
  for (int d = lane; d < D; d += 64) {
    float ej = ep[(size_t)j * D + d];
    dot += ep[(size_t)i * D + d] * ej;
    bil += epw[(size_t)i * D + d] * ej;
  }
  dot = warp_reduce_sum(dot);
  bil = warp_reduce_sum(bil);
  if (lane == 0) {
    attn_in[0 * NPIX + pi] = dot;
    attn_in[1 * NPIX + pi] = dot / ((norms[i] + 1e-13f) * (norms[j] + 1e-13f));
    attn_in[2 * NPIX + pi] = bil + b_bil[0];
  }
}

// ---------------- conv1: 3->256, 3x3 SAME, relu ----------------
__global__ __launch_bounds__(256) void conv1_kernel(
    const float* __restrict__ attn_in, const float* __restrict__ w,
    const float* __restrict__ bias, float* __restrict__ h1) {
  int o = blockIdx.y;
  int p = blockIdx.x * 256 + threadIdx.x;
  if (p >= NPIX) return;
  int y = p / EPAD, x = p % EPAD;
  float wv[27];
#pragma unroll
  for (int i = 0; i < 27; ++i) wv[i] = w[o * 27 + i];
  float acc = bias[o];
#pragma unroll
  for (int ci = 0; ci < 3; ++ci)
#pragma unroll
    for (int ky = 0; ky < 3; ++ky) {
      int gy = y - 1 + ky;
      if (gy < 0 || gy >= EPAD) continue;
#pragma unroll
      for (int kx = 0; kx < 3; ++kx) {
        int gx = x - 1 + kx;
        if (gx < 0 || gx >= EPAD) continue;
        acc += attn_in[ci * NPIX + gy * EPAD + gx] * wv[ci * 9 + ky * 3 + kx];
      }
    }
  h1[(size_t)o * NPIX + p] = fmaxf(acc, 0.f);
}

// ---------------- conv2: 256->256, 3x3 SAME, relu (LDS-tiled) ----------------
__global__ __launch_bounds__(256) void conv2_kernel(
    const float* __restrict__ h1, const float* __restrict__ w,
    const float* __restrict__ bias, float* __restrict__ h2) {
  __shared__ float sin_[4][34][34];
  __shared__ float sw[4][9][16];
  int tid = threadIdx.x;
  int y0 = blockIdx.y * 32, x0 = blockIdx.x * 32, o0 = blockIdx.z * 16;
  int ty = tid >> 4, txl = tid & 15;
  int py = ty * 2, px = txl * 2;
  float acc[2][2][16] = {};
  for (int c0 = 0; c0 < C1; c0 += 4) {
    __syncthreads();
    for (int li = tid; li < 4 * 34 * 34; li += 256) {
      int c = li / 1156, r = li % 1156;
      int iy = r / 34, ix = r % 34;
      int gy = y0 - 1 + iy, gx = x0 - 1 + ix;
      sin_[c][iy][ix] = (gy >= 0 && gy < EPAD && gx >= 0 && gx < EPAD)
                            ? h1[(size_t)(c0 + c) * NPIX + gy * EPAD + gx]
                            : 0.f;
    }
    // FIX (round 2): sw has 4*9*16 = 576 entries but only 256 threads;
    // a guarded single-shot load left entries 256..575 as stale LDS
    // garbage -> ~1% contamination of final logits via conv2->ht0->ht1.
    for (int li = tid; li < 4 * 9 * 16; li += 256) {
      int c = li / 144, rem = li % 144, kk = rem / 16, o = rem % 16;
      sw[c][kk][o] = w[((size_t)(o0 + o) * C1 + (c0 + c)) * 9 + kk];
    }
    __syncthreads();
#pragma unroll
    for (int c = 0; c < 4; ++c)
#pragma unroll
      for (int ky = 0; ky < 3; ++ky)
#pragma unroll
        for (int kx = 0; kx < 3; ++kx) {
          float wr[16];
#pragma unroll
          for (int o = 0; o < 16; ++o) wr[o] = sw[c][ky * 3 + kx][o];
#pragma unroll
          for (int dy = 0; dy < 2; ++dy)
#pragma unroll
            for (int dx = 0; dx < 2; ++dx) {
              float inv = sin_[c][py + dy + ky][px + dx + kx];
#pragma unroll
              for (int o = 0; o < 16; ++o) acc[dy][dx][o] += inv * wr[o];
            }
        }
  }
#pragma unroll
  for (int dy = 0; dy < 2; ++dy)
#pragma unroll
    for (int dx = 0; dx < 2; ++dx) {
      int gy = y0 + py + dy, gx = x0 + px + dx;
      if (gy < EPAD && gx < EPAD)
#pragma unroll
        for (int o = 0; o < 16; ++o)
          h2[(size_t)(o0 + o) * NPIX + gy * EPAD + gx] =
              fmaxf(acc[dy][dx][o] + bias[o0 + o], 0.f);
    }
}

// ---------------- gather ht0 from conv map ----------------
__global__ void gather_ht0_kernel(const float* __restrict__ h2,
                                  const int* __restrict__ htp,
                                  float* __restrict__ ht0) {
  int p = blockIdx.x;
  int y = htp[p * 2 + 0], x = htp[p * 2 + 1];
  int c = threadIdx.x;
  ht0[(size_t)p * C1 + c] = h2[(size_t)c * NPIX + y * EPAD + x];
}

// ---------------- hs/ts = tanh(concat(e, ht1)) ----------------
__global__ void pair_feats_kernel(const float* __restrict__ ent,
                                  const int* __restrict__ htp,
                                  const float* __restrict__ ht1,
                                  float* __restrict__ hs, float* __restrict__ ts) {
  int p = blockIdx.x;
  int e1 = htp[p * 2 + 0], e2 = htp[p * 2 + 1];
  for (int d = threadIdx.x; d < D; d += 256) {
    hs[(size_t)p * 832 + d] = tanhf(ent[(size_t)e1 * D + d]);
    ts[(size_t)p * 832 + d] = tanhf(ent[(size_t)e2 * D + d]);
  }
  if (threadIdx.x < 64) {
    float v = tanhf(ht1[p * 64 + threadIdx.x]);
    hs[(size_t)p * 832 + D + threadIdx.x] = v;
    ts[(size_t)p * 832 + D + threadIdx.x] = v;
  }
}

// ---------------- final: out[p,:] = (b1 outer b2) @ W_cls + b_cls ----------------
__global__ __launch_bounds__(256) void final_kernel(
    const float* __restrict__ hs, const float* __restrict__ ts,
    const float* __restrict__ Wc, const float* __restrict__ bc,
    float* __restrict__ out) {
  __shared__ float sh[832];
  __shared__ float st[832];
  __shared__ float sacc[5][4];
  int p = blockIdx.x, tid = threadIdx.x;
  for (int i = tid; i < 832; i += 256) {
    sh[i] = hs[(size_t)p * 832 + i];
    st[i] = ts[(size_t)p * 832 + i];
  }
  __syncthreads();
  float acc[5] = {};
  for (int idx = tid; idx < 13 * 64 * 64; idx += 256) {
    int g = idx >> 12;
    int a = (idx >> 6) & 63, b2 = idx & 63;
    float v = sh[g * 64 + a] * st[g * 64 + b2];
    const float* wr = Wc + (size_t)idx * 5;
    acc[0] += v * wr[0];
    acc[1] += v * wr[1];
    acc[2] += v * wr[2];
    acc[3] += v * wr[3];
    acc[4] += v * wr[4];
  }
#pragma unroll
  for (int c = 0; c < 5; ++c) {
    float r = warp_reduce_sum(acc[c]);
    if ((tid & 63) == 0) sacc[c][tid >> 6] = r;
  }
  __syncthreads();
  if (tid < 5)
    out[p * 5 + tid] = sacc[tid][0] + sacc[tid][1] + sacc[tid][2] + sacc[tid][3] + bc[tid];
}

// ---------------- host orchestration ----------------
extern "C" void kernel_launch(void* const* d_in, const int* in_sizes, int n_in,
                              void* d_out, int out_size, void* d_ws, size_t ws_size,
                              hipStream_t stream) {
  const int* ids = (const int*)d_in[0];
  const float* masks = (const float*)d_in[1];
  const int* span_idx = (const int*)d_in[2];
  const int* mids = (const int*)d_in[3];
  const int* eom = (const int*)d_in[4];
  const int* htp = (const int*)d_in[5];
  const float* emb = (const float*)d_in[6];
  const float* pos = (const float*)d_in[7];
  const float* ln_emb_g = (const float*)d_in[8];
  const float* ln_emb_b = (const float*)d_in[9];
  const float* Wq = (const float*)d_in[10];
  const float* Wk = (const float*)d_in[11];
  const float* Wv = (const float*)d_in[12];
  const float* Wo = (const float*)d_in[13];
  const float* bq = (const float*)d_in[14];
  const float* bk = (const float*)d_in[15];
  const float* bv = (const float*)d_in[16];
  const float* bo = (const float*)d_in[17];
  const float* ln1_g = (const float*)d_in[18];
  const float* ln1_b = (const float*)d_in[19];
  const float* Wff1 = (const float*)d_in[20];
  const float* bff1 = (const float*)d_in[21];
  const float* Wff2 = (const float*)d_in[22];
  const float* bff2 = (const float*)d_in[23];
  const float* ln2_g = (const float*)d_in[24];
  const float* ln2_b = (const float*)d_in[25];
  const float* c1w = (const float*)d_in[26];
  const float* c1b = (const float*)d_in[27];
  const float* c2w = (const float*)d_in[28];
  const float* c2b = (const float*)d_in[29];
  const float* Wbil = (const float*)d_in[30];
  const float* bbil = (const float*)d_in[31];
  const float* Wue = (const float*)d_in[32];
  const float* bue = (const float*)d_in[33];
  const float* Wcls = (const float*)d_in[34];
  const float* bcls = (const float*)d_in[35];
  float* out = (float*)d_out;
  float* ws = (float*)d_ws;

  const size_t XSZ = (size_t)NT * D;  // 1966080
  float* x = ws;
  float* q = ws + XSZ;       // also reused as ctx
  float* kbuf = ws + 2 * XSZ;  // also reused as tmp / ht1
  float* vbuf = ws + 3 * XSZ;  // also reused as entity scratch
  float* big = ws + 4 * XSZ;   // 7864320 floats: scores_b / ff / h1+h2
  float* scores = big;
  float* ff = big;
  float* tmp = kbuf;
  float* ctx = q;
  float* h1 = big;
  float* h2 = big + (size_t)C1 * NPIX;

  // entity scratch inside vbuf
  float* m_sum = vbuf;
  float* m_cnt = m_sum + (size_t)M_N * D;
  float* e_sum = m_cnt + M_N;
  float* e_cnt = e_sum + (size_t)E_N * D;
  int* last_m = (int*)(e_cnt + E_N);
  float* ent = (float*)(last_m + E_N);
  float* ep = ent + (size_t)E_N * D;
  float* epw = ep + (size_t)EPAD * D;
  float* norms = epw + (size_t)EPAD * D;
  float* attn_in = norms + EPAD;
  float* ht0 = attn_in + 3 * NPIX;
  float* hs = ht0 + (size_t)P_N * C1;
  float* tsb = hs + (size_t)P_N * 832;
  float* ht1 = kbuf;

  auto GEMM = [&](const float* A, int lda, const float* B, int ldb, float* C,
                  int ldc, int Md, int Nd, int Kd, const float* bias, int act) {
    dim3 grid((Nd + 63) / 64, (Md + 63) / 64);
    hipLaunchKernelGGL(gemm_f32, grid, dim3(256), 0, stream, A, lda, B, ldb, C,
                       ldc, Md, Nd, Kd, bias, act);
  };

  embed_ln_kernel<<<NT, 256, 0, stream>>>(ids, emb, pos, ln_emb_g, ln_emb_b, x);

  for (int l = 0; l < LNUM; ++l) {
    const size_t WDD = (size_t)D * D;
    GEMM(x, D, Wq + l * WDD, D, q, D, NT, D, D, bq + l * D, 0);
    GEMM(x, D, Wk + l * WDD, D, kbuf, D, NT, D, D, bk + l * D, 0);
    GEMM(x, D, Wv + l * WDD, D, vbuf, D, NT, D, D, bv + l * D, 0);
    for (int b = 0; b < NSEQ; ++b) {
      attn_scores_kernel<<<dim3(8, 8, H), 256, 0, stream>>>(q, kbuf, masks, scores, b);
      softmax_kernel<<<H * S, 256, 0, stream>>>(scores);
      attn_ctx_kernel<<<dim3(1, 8, H), 256, 0, stream>>>(scores, vbuf, ctx, b);
    }
    GEMM(ctx, D, Wo + l * WDD, D, tmp, D, NT, D, D, bo + l * D, 0);
    add_ln_kernel<<<NT, 256, 0, stream>>>(x, tmp, ln1_g + l * D, ln1_b + l * D);
    GEMM(x, D, Wff1 + (size_t)l * D * FFD, FFD, ff, FFD, NT, FFD, D, bff1 + l * FFD, 1);
    GEMM(ff, FFD, Wff2 + (size_t)l * FFD * D, D, tmp, D, NT, D, FFD, bff2 + l * D, 0);
    add_ln_kernel<<<NT, 256, 0, stream>>>(x, tmp, ln2_g + l * D, ln2_b + l * D);
  }

  // zero atomic accumulators + ep padding (d_ws is poisoned before every call)
  size_t zero_bytes = (size_t)((char*)(ep + (size_t)EPAD * D) - (char*)m_sum);
  hipMemsetAsync(m_sum, 0, zero_bytes, stream);

  seg_mention_kernel<<<T_N, 256, 0, stream>>>(x, span_idx, mids, m_sum, m_cnt);
  m_div_kernel<<<(M_N * D + 255) / 256, 256, 0, stream>>>(m_sum, m_cnt);
  seg_entity_kernel<<<M_N, 256, 0, stream>>>(m_sum, eom, e_sum, e_cnt, last_m);
  ent_make_kernel<<<E_N, 256, 0, stream>>>(e_sum, e_cnt, last_m, m_sum, ent, ep);
  row_norms_kernel<<<EPAD, 256, 0, stream>>>(ep, norms);
  GEMM(ep, D, Wbil, D, epw, D, EPAD, D, D, nullptr, 0);
  pair_maps_kernel<<<NPIX / 4, 256, 0, stream>>>(ep, epw, norms, bbil, attn_in);
  conv1_kernel<<<dim3((NPIX + 255) / 256, C1), 256, 0, stream>>>(attn_in, c1w, c1b, h1);
  conv2_kernel<<<dim3(4, 4, 16), 256, 0, stream>>>(h1, c2w, c2b, h2);
  gather_ht0_kernel<<<P_N, 256, 0, stream>>>(h2, htp, ht0);
  GEMM(ht0, C1, Wue, 64, ht1, 64, P_N, 64, C1, bue, 0);
  pair_feats_kernel<<<P_N, 256, 0, stream>>>(ent, htp, ht1, hs, tsb);
  final_kernel<<<P_N, 256, 0, stream>>>(hs, tsb, Wcls, bcls, out);
}

// Round 9
// 2083.960 us; speedup vs baseline: 2.2961x; 2.2961x over previous
//
#include <hip/hip_runtime.h>
#include <math.h>

#define LNUM 4
#define H 12
#define D 768
#define DH 64
#define FFD 3072
#define S 512
#define NSEQ 5
#define NT (NSEQ*S)
#define E_N 100
#define M_N 300
#define T_N 900
#define P_N 400
#define EPAD 120
#define NPIX (EPAD*EPAD)
#define C1 256

typedef unsigned short ushortT;
typedef short bf16x8 __attribute__((ext_vector_type(8)));
typedef float f32x4 __attribute__((ext_vector_type(4)));

__device__ __forceinline__ ushortT f2b(float f) {
  union { float f; unsigned u; } v; v.f = f;
  unsigned r = v.u + 0x7FFFu + ((v.u >> 16) & 1u);
  return (ushortT)(r >> 16);
}
__device__ __forceinline__ float b2f(ushortT u) {
  union { unsigned u; float f; } v; v.u = ((unsigned)u) << 16; return v.f;
}

// ---------------- reduction helpers (blockDim == 256) ----------------
__device__ __forceinline__ float warp_reduce_sum(float v) {
#pragma unroll
  for (int off = 32; off > 0; off >>= 1) v += __shfl_down(v, off, 64);
  return v;
}
__device__ __forceinline__ float warp_reduce_max(float v) {
#pragma unroll
  for (int off = 32; off > 0; off >>= 1) v = fmaxf(v, __shfl_down(v, off, 64));
  return v;
}
__device__ __forceinline__ float block_sum(float v, float* sb) {
  v = warp_reduce_sum(v);
  __syncthreads();
  if ((threadIdx.x & 63) == 0) sb[threadIdx.x >> 6] = v;
  __syncthreads();
  if (threadIdx.x == 0) sb[0] = sb[0] + sb[1] + sb[2] + sb[3];
  __syncthreads();
  return sb[0];
}

// ---------------- embedding + LN (writes f32 + bf16) ----------------
__global__ __launch_bounds__(256) void embed_ln_kernel(
    const int* __restrict__ ids, const float* __restrict__ emb,
    const float* __restrict__ pos, const float* __restrict__ g,
    const float* __restrict__ b, float* __restrict__ x, ushortT* __restrict__ xb) {
  __shared__ float sv[D];
  __shared__ float sb[4];
  int t = blockIdx.x;
  int s = t % S;
  int id = ids[t];
  float lsum = 0.f;
  for (int d = threadIdx.x; d < D; d += 256) {
    float val = emb[(size_t)id * D + d] + pos[(size_t)s * D + d];
    sv[d] = val;
    lsum += val;
  }
  float mean = block_sum(lsum, sb) * (1.f / D);
  float lvar = 0.f;
  for (int d = threadIdx.x; d < D; d += 256) {
    float c = sv[d] - mean;
    lvar += c * c;
  }
  float rstd = rsqrtf(block_sum(lvar, sb) * (1.f / D) + 1e-12f);
  for (int d = threadIdx.x; d < D; d += 256) {
    float o = (sv[d] - mean) * rstd * g[d] + b[d];
    x[(size_t)t * D + d] = o;
    xb[(size_t)t * D + d] = f2b(o);
  }
}

// ---------------- x = LN(x + tmp), writes f32 + bf16 ----------------
__global__ __launch_bounds__(256) void add_ln_kernel(
    float* __restrict__ x, const float* __restrict__ tmp,
    const float* __restrict__ g, const float* __restrict__ b,
    ushortT* __restrict__ xb) {
  __shared__ float sv[D];
  __shared__ float sb[4];
  int t = blockIdx.x;
  float lsum = 0.f;
  for (int d = threadIdx.x; d < D; d += 256) {
    float v = x[(size_t)t * D + d] + tmp[(size_t)t * D + d];
    sv[d] = v;
    lsum += v;
  }
  float mean = block_sum(lsum, sb) * (1.f / D);
  float lvar = 0.f;
  for (int d = threadIdx.x; d < D; d += 256) {
    float c = sv[d] - mean;
    lvar += c * c;
  }
  float rstd = rsqrtf(block_sum(lvar, sb) * (1.f / D) + 1e-12f);
  for (int d = threadIdx.x; d < D; d += 256) {
    float o = (sv[d] - mean) * rstd * g[d] + b[d];
    x[(size_t)t * D + d] = o;
    xb[(size_t)t * D + d] = f2b(o);
  }
}

// ---------------- weight convert+transpose: f32 [K][N] -> bf16 [N][K] ----------------
__global__ __launch_bounds__(256) void wcvt_t_kernel(
    const float* __restrict__ W, ushortT* __restrict__ WT, int Kd, int Nd) {
  __shared__ ushortT tile[32][33];
  int k0 = blockIdx.y * 32, n0 = blockIdx.x * 32;
  int tx = threadIdx.x & 31, ty = threadIdx.x >> 5;
#pragma unroll
  for (int i = 0; i < 32; i += 8)
    tile[ty + i][tx] = f2b(W[(size_t)(k0 + ty + i) * Nd + n0 + tx]);
  __syncthreads();
#pragma unroll
  for (int i = 0; i < 32; i += 8)
    WT[(size_t)(n0 + ty + i) * Kd + k0 + tx] = tile[tx][ty + i];
}

// ---------------- bf16 MFMA GEMM: C = act(A @ BT^T + bias) ----------------
// A [M][K] bf16 (lda), BT [N][K] bf16 (ldb). M,N % 128 == 0, K % 64 == 0.
__global__ __launch_bounds__(256) void gemm_bf16(
    const ushortT* __restrict__ A, int lda,
    const ushortT* __restrict__ BT, int ldb,
    float* __restrict__ Cf, ushortT* __restrict__ Cb, int ldc,
    int Kd, const float* __restrict__ bias, int act) {
  __shared__ __align__(16) ushortT As[128 * 64];
  __shared__ __align__(16) ushortT Bs[128 * 64];
  int tid = threadIdx.x, wid = tid >> 6, lane = tid & 63;
  int row0 = blockIdx.y * 128, col0 = blockIdx.x * 128;
  int lrow = lane & 15;
  int wm = (wid & 1) * 64, wn = (wid >> 1) * 64;
  f32x4 acc[4][4] = {};
  for (int k0 = 0; k0 < Kd; k0 += 64) {
#pragma unroll
    for (int j = 0; j < 4; ++j) {
      int L = tid + j * 256;
      int r = L >> 3, ck = L & 7;
      *(bf16x8*)&As[((r << 3) + (ck ^ (r & 7))) << 3] =
          *(const bf16x8*)(A + (size_t)(row0 + r) * lda + k0 + ck * 8);
      *(bf16x8*)&Bs[((r << 3) + (ck ^ (r & 7))) << 3] =
          *(const bf16x8*)(BT + (size_t)(col0 + r) * ldb + k0 + ck * 8);
    }
    __syncthreads();
#pragma unroll
    for (int ks = 0; ks < 2; ++ks) {
      int c = ks * 4 + (lane >> 4);
      bf16x8 af[4], bfr[4];
#pragma unroll
      for (int f = 0; f < 4; ++f) {
        int ra = wm + f * 16 + lrow;
        af[f] = *(const bf16x8*)&As[((ra << 3) + (c ^ (ra & 7))) << 3];
        int rb = wn + f * 16 + lrow;
        bfr[f] = *(const bf16x8*)&Bs[((rb << 3) + (c ^ (rb & 7))) << 3];
      }
#pragma unroll
      for (int m = 0; m < 4; ++m)
#pragma unroll
        for (int n = 0; n < 4; ++n)
          acc[m][n] = __builtin_amdgcn_mfma_f32_16x16x32_bf16(af[m], bfr[n], acc[m][n], 0, 0, 0);
    }
    __syncthreads();
  }
#pragma unroll
  for (int m = 0; m < 4; ++m)
#pragma unroll
    for (int i = 0; i < 4; ++i) {
      int r = row0 + wm + m * 16 + (lane >> 4) * 4 + i;
#pragma unroll
      for (int n = 0; n < 4; ++n) {
        int cc = col0 + wn + n * 16 + lrow;
        float v = acc[m][n][i];
        if (bias) v += bias[cc];
        if (act == 1) {
          float x3 = v * v * v;
          v = 0.5f * v * (1.f + tanhf(0.79788456080286535588f * (v + 0.044715f * x3)));
        }
        if (Cf) Cf[(size_t)r * ldc + cc] = v;
        if (Cb) Cb[(size_t)r * ldc + cc] = f2b(v);
      }
    }
}

// ---------------- attention scores (MFMA), one sequence b: scb[hh][i][j] ----------------
__global__ __launch_bounds__(256) void attn_scores_mfma(
    const ushortT* __restrict__ qb, const ushortT* __restrict__ kb,
    const float* __restrict__ mask, ushortT* __restrict__ scb, int b) {
  __shared__ __align__(16) ushortT Qs[128 * 64];
  __shared__ __align__(16) ushortT Ks[128 * 64];
  int tid = threadIdx.x, wid = tid >> 6, lane = tid & 63;
  int hh = blockIdx.z;
  int i0 = blockIdx.y * 128, j0 = blockIdx.x * 128;
  const ushortT* Qg = qb + ((size_t)b * S + i0) * D + hh * DH;
  const ushortT* Kg = kb + ((size_t)b * S + j0) * D + hh * DH;
#pragma unroll
  for (int j = 0; j < 4; ++j) {
    int L = tid + j * 256;
    int r = L >> 3, ck = L & 7;
    *(bf16x8*)&Qs[((r << 3) + (ck ^ (r & 7))) << 3] =
        *(const bf16x8*)(Qg + (size_t)r * D + ck * 8);
    *(bf16x8*)&Ks[((r << 3) + (ck ^ (r & 7))) << 3] =
        *(const bf16x8*)(Kg + (size_t)r * D + ck * 8);
  }
  __syncthreads();
  int lrow = lane & 15;
  int wm = (wid & 1) * 64, wn = (wid >> 1) * 64;
  f32x4 acc[4][4] = {};
#pragma unroll
  for (int ks = 0; ks < 2; ++ks) {
    int c = ks * 4 + (lane >> 4);
    bf16x8 af[4], bfr[4];
#pragma unroll
    for (int f = 0; f < 4; ++f) {
      int ra = wm + f * 16 + lrow;
      af[f] = *(const bf16x8*)&Qs[((ra << 3) + (c ^ (ra & 7))) << 3];
      int rb = wn + f * 16 + lrow;
      bfr[f] = *(const bf16x8*)&Ks[((rb << 3) + (c ^ (rb & 7))) << 3];
    }
#pragma unroll
    for (int m = 0; m < 4; ++m)
#pragma unroll
      for (int n = 0; n < 4; ++n)
        acc[m][n] = __builtin_amdgcn_mfma_f32_16x16x32_bf16(af[m], bfr[n], acc[m][n], 0, 0, 0);
  }
  float mb[4];
#pragma unroll
  for (int n = 0; n < 4; ++n) {
    int jj = j0 + wn + n * 16 + lrow;
    mb[n] = (1.f - mask[(size_t)b * S + jj]) * -1e9f;
  }
  ushortT* outz = scb + (size_t)hh * S * S;
#pragma unroll
  for (int m = 0; m < 4; ++m)
#pragma unroll
    for (int i = 0; i < 4; ++i) {
      int ii = i0 + wm + m * 16 + (lane >> 4) * 4 + i;
      ushortT* orow = outz + (size_t)ii * S + j0 + wn;
#pragma unroll
      for (int n = 0; n < 4; ++n)
        orow[n * 16 + lrow] = f2b(acc[m][n][i] * 0.125f + mb[n]);
    }
}

// ---------------- softmax over rows of 512 (bf16 in-place) ----------------
__global__ __launch_bounds__(256) void attn_softmax_bf16(ushortT* __restrict__ scb) {
  __shared__ float sb[4];
  ushortT* p = scb + (size_t)blockIdx.x * S;
  int tid = threadIdx.x;
  float v0 = b2f(p[tid]), v1 = b2f(p[tid + 256]);
  float mx = warp_reduce_max(fmaxf(v0, v1));
  __syncthreads();
  if ((tid & 63) == 0) sb[tid >> 6] = mx;
  __syncthreads();
  float bm = fmaxf(fmaxf(sb[0], sb[1]), fmaxf(sb[2], sb[3]));
  float e0 = expf(v0 - bm), e1 = expf(v1 - bm);
  float s = block_sum(e0 + e1, sb);
  float inv = 1.f / s;
  p[tid] = f2b(e0 * inv);
  p[tid + 256] = f2b(e1 * inv);
}

// ---------------- V transpose (one sequence b): vb -> vt[hh][n][k] ----------------
__global__ __launch_bounds__(256) void vt_kernel(const ushortT* __restrict__ vb,
                                                 ushortT* __restrict__ vt, int b) {
  __shared__ ushortT tile[32][33];
  int hh = blockIdx.z;
  int k0 = blockIdx.y * 32, n0 = blockIdx.x * 32;
  int tx = threadIdx.x & 31, ty = threadIdx.x >> 5;
#pragma unroll
  for (int i = 0; i < 32; i += 8)
    tile[ty + i][tx] = vb[((size_t)b * S + k0 + ty + i) * D + hh * DH + n0 + tx];
  __syncthreads();
#pragma unroll
  for (int i = 0; i < 32; i += 8)
    vt[((size_t)hh * DH + n0 + ty + i) * S + k0 + tx] = tile[tx][ty + i];
}

// ---------------- P @ V (MFMA), one sequence b ----------------
__global__ __launch_bounds__(256) void attn_pv_mfma(
    const ushortT* __restrict__ scb, const ushortT* __restrict__ vt,
    ushortT* __restrict__ ctxb, int b) {
  __shared__ __align__(16) ushortT Ps[128 * 64];
  __shared__ __align__(16) ushortT VTs[64 * 64];
  int tid = threadIdx.x, wid = tid >> 6, lane = tid & 63;
  int hh = blockIdx.y;
  int i0 = blockIdx.x * 128;
  const ushortT* A = scb + ((size_t)hh * S + i0) * S;
  const ushortT* vtz = vt + (size_t)hh * DH * S;
  int lrow = lane & 15;
  int wm = wid * 32;
  f32x4 acc[2][4] = {};
  for (int k0 = 0; k0 < S; k0 += 64) {
#pragma unroll
    for (int j = 0; j < 4; ++j) {
      int L = tid + j * 256;
      int r = L >> 3, ck = L & 7;
      *(bf16x8*)&Ps[((r << 3) + (ck ^ (r & 7))) << 3] =
          *(const bf16x8*)(A + (size_t)r * S + k0 + ck * 8);
    }
#pragma unroll
    for (int j = 0; j < 2; ++j) {
      int L = tid + j * 256;
      int r = L >> 3, ck = L & 7;
      *(bf16x8*)&VTs[((r << 3) + (ck ^ (r & 7))) << 3] =
          *(const bf16x8*)(vtz + (size_t)r * S + k0 + ck * 8);
    }
    __syncthreads();
#pragma unroll
    for (int ks = 0; ks < 2; ++ks) {
      int c = ks * 4 + (lane >> 4);
      bf16x8 af[2], bfr[4];
#pragma unroll
      for (int f = 0; f < 2; ++f) {
        int ra = wm + f * 16 + lrow;
        af[f] = *(const bf16x8*)&Ps[((ra << 3) + (c ^ (ra & 7))) << 3];
      }
#pragma unroll
      for (int f = 0; f < 4; ++f) {
        int rb = f * 16 + lrow;
        bfr[f] = *(const bf16x8*)&VTs[((rb << 3) + (c ^ (rb & 7))) << 3];
      }
#pragma unroll
      for (int m = 0; m < 2; ++m)
#pragma unroll
        for (int n = 0; n < 4; ++n)
          acc[m][n] = __builtin_amdgcn_mfma_f32_16x16x32_bf16(af[m], bfr[n], acc[m][n], 0, 0, 0);
    }
    __syncthreads();
  }
#pragma unroll
  for (int m = 0; m < 2; ++m)
#pragma unroll
    for (int i = 0; i < 4; ++i) {
      int ii = i0 + wm + m * 16 + (lane >> 4) * 4 + i;
#pragma unroll
      for (int n = 0; n < 4; ++n) {
        int cc = n * 16 + lrow;
        ctxb[((size_t)b * S + ii) * D + hh * DH + cc] = f2b(acc[m][n][i]);
      }
    }
}

// ---------------- generic fp32 tiled GEMM (small tail GEMMs) ----------------
__global__ __launch_bounds__(256) void gemm_f32(
    const float* __restrict__ A, int lda, const float* __restrict__ B, int ldb,
    float* __restrict__ C, int ldc, int Md, int Nd, int Kd,
    const float* __restrict__ bias, int act) {
  __shared__ float As[16][68];
  __shared__ float Bs[16][68];
  int tid = threadIdx.x;
  int tx = tid & 15, ty = tid >> 4;
  int row0 = blockIdx.y * 64, col0 = blockIdx.x * 64;
  int ar = tid >> 2, ak = (tid & 3) * 4;
  int br = tid >> 4, bc = (tid & 15) * 4;
  float acc[4][4] = {};
  for (int k0 = 0; k0 < Kd; k0 += 16) {
    float4 av = make_float4(0.f, 0.f, 0.f, 0.f);
    if (row0 + ar < Md)
      av = *(const float4*)(A + (size_t)(row0 + ar) * lda + k0 + ak);
    float4 bv = make_float4(0.f, 0.f, 0.f, 0.f);
    if (col0 + bc < Nd)
      bv = *(const float4*)(B + (size_t)(k0 + br) * ldb + col0 + bc);
    As[ak + 0][ar] = av.x;
    As[ak + 1][ar] = av.y;
    As[ak + 2][ar] = av.z;
    As[ak + 3][ar] = av.w;
    *(float4*)&Bs[br][bc] = bv;
    __syncthreads();
#pragma unroll
    for (int kk = 0; kk < 16; ++kk) {
      float4 a4 = *(const float4*)&As[kk][ty * 4];
      float4 b4 = *(const float4*)&Bs[kk][tx * 4];
      float aa[4] = {a4.x, a4.y, a4.z, a4.w};
      float bb[4] = {b4.x, b4.y, b4.z, b4.w};
#pragma unroll
      for (int m = 0; m < 4; ++m)
#pragma unroll
        for (int n = 0; n < 4; ++n) acc[m][n] += aa[m] * bb[n];
    }
    __syncthreads();
  }
#pragma unroll
  for (int m = 0; m < 4; ++m) {
    int r = row0 + ty * 4 + m;
    if (r >= Md) continue;
#pragma unroll
    for (int n = 0; n < 4; ++n) {
      int c = col0 + tx * 4 + n;
      if (c >= Nd) continue;
      float v = acc[m][n];
      if (bias) v += bias[c];
      C[(size_t)r * ldc + c] = v;
    }
  }
}

// ---------------- segment ops ----------------
__global__ void seg_mention_kernel(const float* __restrict__ x,
                                   const int* __restrict__ span_idx,
                                   const int* __restrict__ mids,
                                   float* m_sum, float* m_cnt) {
  int t = blockIdx.x;
  int tok = span_idx[t];
  int m = mids[t];
  for (int d = threadIdx.x; d < D; d += 256)
    atomicAdd(&m_sum[(size_t)m * D + d], x[(size_t)tok * D + d]);
  if (threadIdx.x == 0) atomicAdd(&m_cnt[m], 1.f);
}

__global__ void m_div_kernel(float* m_sum, const float* m_cnt) {
  int i = blockIdx.x * 256 + threadIdx.x;
  if (i < M_N * D) m_sum[i] /= m_cnt[i / D];
}

__global__ void seg_entity_kernel(const float* __restrict__ m_emb,
                                  const int* __restrict__ eom, float* e_sum,
                                  float* e_cnt, int* last_m) {
  int m = blockIdx.x;
  int e = eom[m];
  for (int d = threadIdx.x; d < D; d += 256)
    atomicAdd(&e_sum[(size_t)e * D + d], m_emb[(size_t)m * D + d]);
  if (threadIdx.x == 0) {
    atomicAdd(&e_cnt[e], 1.f);
    atomicMax(&last_m[e], m);
  }
}

__global__ void ent_make_kernel(const float* e_sum, const float* e_cnt,
                                const int* last_m, const float* m_emb,
                                float* ent, float* ep) {
  int e = blockIdx.x;
  int lm = last_m[e];
  float inv = 1.f / e_cnt[e];
  for (int d = threadIdx.x; d < D; d += 256) {
    float v = (e_sum[(size_t)e * D + d] + m_emb[(size_t)lm * D + d]) * inv;
    ent[(size_t)e * D + d] = v;
    ep[(size_t)e * D + d] = v;
  }
}

__global__ __launch_bounds__(256) void row_norms_kernel(const float* ep, float* norms) {
  __shared__ float sb[4];
  int r = blockIdx.x;
  float s = 0.f;
  for (int d = threadIdx.x; d < D; d += 256) {
    float v = ep[(size_t)r * D + d];
    s += v * v;
  }
  s = block_sum(s, sb);
  if (threadIdx.x == 0) norms[r] = sqrtf(s);
}

// ---------------- pairwise maps: dot / cos / bil ----------------
__global__ __launch_bounds__(256) void pair_maps_kernel(
    const float* __restrict__ ep, const float* __restrict__ epw,
    const float* __restrict__ norms, const float* __restrict__ b_bil,
    float* __restrict__ attn_in) {
  int wv = threadIdx.x >> 6, lane = threadIdx.x & 63;
  int pi = blockIdx.x * 4 + wv;
  int i = pi / EPAD, j = pi % EPAD;
  float dot = 0.f, bil = 0.f;
  for (int d = lane; d < D; d += 64) {
    float ej = ep[(size_t)j * D + d];
    dot += ep[(size_t)i * D + d] * ej;
    bil += epw[(size_t)i * D + d] * ej;
  }
  dot = warp_reduce_sum(dot);
  bil = warp_reduce_sum(bil);
  if (lane == 0) {
    attn_in[0 * NPIX + pi] = dot;
    attn_in[1 * NPIX + pi] = dot / ((norms[i] + 1e-13f) * (norms[j] + 1e-13f));
    attn_in[2 * NPIX + pi] = bil + b_bil[0];
  }
}

// ---------------- conv1: 3->256, 3x3 SAME, relu ----------------
__global__ __launch_bounds__(256) void conv1_kernel(
    const float* __restrict__ attn_in, const float* __restrict__ w,
    const float* __restrict__ bias, float* __restrict__ h1) {
  int o = blockIdx.y;
  int p = blockIdx.x * 256 + threadIdx.x;
  if (p >= NPIX) return;
  int y = p / EPAD, x = p % EPAD;
  float wv[27];
#pragma unroll
  for (int i = 0; i < 27; ++i) wv[i] = w[o * 27 + i];
  float acc = bias[o];
#pragma unroll
  for (int ci = 0; ci < 3; ++ci)
#pragma unroll
    for (int ky = 0; ky < 3; ++ky) {
      int gy = y - 1 + ky;
      if (gy < 0 || gy >= EPAD) continue;
#pragma unroll
      for (int kx = 0; kx < 3; ++kx) {
        int gx = x - 1 + kx;
        if (gx < 0 || gx >= EPAD) continue;
        acc += attn_in[ci * NPIX + gy * EPAD + gx] * wv[ci * 9 + ky * 3 + kx];
      }
    }
  h1[(size_t)o * NPIX + p] = fmaxf(acc, 0.f);
}

// ---------------- conv2 weight transpose: [256][2304] -> [2304][256] ----------------
__global__ __launch_bounds__(256) void w2t_kernel(const float* __restrict__ w,
                                                  float* __restrict__ wt) {
  __shared__ float t[32][33];
  int j0 = blockIdx.x * 32, o0 = blockIdx.y * 32;
  int tx = threadIdx.x & 31, ty = threadIdx.x >> 5;
#pragma unroll
  for (int i = 0; i < 32; i += 8)
    t[ty + i][tx] = w[(size_t)(o0 + ty + i) * 2304 + j0 + tx];
  __syncthreads();
#pragma unroll
  for (int i = 0; i < 32; i += 8)
    wt[(size_t)(j0 + ty + i) * 256 + o0 + tx] = t[tx][ty + i];
}

// ---------------- conv2 evaluated only at the 400 pair locations ----------------
__global__ __launch_bounds__(256) void pair_conv2_kernel(
    const float* __restrict__ h1, const float* __restrict__ w2t,
    const float* __restrict__ bias, const int* __restrict__ htp,
    float* __restrict__ ht0) {
  __shared__ float sin_[2304];
  int p = blockIdx.x;
  int y = htp[p * 2 + 0], xx = htp[p * 2 + 1];
  int tid = threadIdx.x;
  for (int li = tid; li < 2304; li += 256) {
    int c = li / 9, kk = li % 9, ky = kk / 3, kx = kk % 3;
    int gy = y - 1 + ky, gx = xx - 1 + kx;
    sin_[li] = (gy >= 0 && gy < EPAD && gx >= 0 && gx < EPAD)
                   ? h1[(size_t)c * NPIX + gy * EPAD + gx]
                   : 0.f;
  }
  __syncthreads();
  float acc = bias[tid];
#pragma unroll 8
  for (int j = 0; j < 2304; ++j) acc += sin_[j] * w2t[(size_t)j * 256 + tid];
  ht0[(size_t)p * C1 + tid] = fmaxf(acc, 0.f);
}

// ---------------- hs/ts = tanh(concat(e, ht1)) ----------------
__global__ void pair_feats_kernel(const float* __restrict__ ent,
                                  const int* __restrict__ htp,
                                  const float* __restrict__ ht1,
                                  float* __restrict__ hs, float* __restrict__ ts) {
  int p = blockIdx.x;
  int e1 = htp[p * 2 + 0], e2 = htp[p * 2 + 1];
  for (int d = threadIdx.x; d < D; d += 256) {
    hs[(size_t)p * 832 + d] = tanhf(ent[(size_t)e1 * D + d]);
    ts[(size_t)p * 832 + d] = tanhf(ent[(size_t)e2 * D + d]);
  }
  if (threadIdx.x < 64) {
    float v = tanhf(ht1[p * 64 + threadIdx.x]);
    hs[(size_t)p * 832 + D + threadIdx.x] = v;
    ts[(size_t)p * 832 + D + threadIdx.x] = v;
  }
}

// ---------------- final: out[p,:] = (b1 outer b2) @ W_cls + b_cls ----------------
__global__ __launch_bounds__(256) void final_kernel(
    const float* __restrict__ hs, const float* __restrict__ ts,
    const float* __restrict__ Wc, const float* __restrict__ bc,
    float* __restrict__ out) {
  __shared__ float sh[832];
  __shared__ float st[832];
  __shared__ float sacc[5][4];
  int p = blockIdx.x, tid = threadIdx.x;
  for (int i = tid; i < 832; i += 256) {
    sh[i] = hs[(size_t)p * 832 + i];
    st[i] = ts[(size_t)p * 832 + i];
  }
  __syncthreads();
  float acc[5] = {};
  for (int idx = tid; idx < 13 * 64 * 64; idx += 256) {
    int g = idx >> 12;
    int a = (idx >> 6) & 63, b2 = idx & 63;
    float v = sh[g * 64 + a] * st[g * 64 + b2];
    const float* wr = Wc + (size_t)idx * 5;
    acc[0] += v * wr[0];
    acc[1] += v * wr[1];
    acc[2] += v * wr[2];
    acc[3] += v * wr[3];
    acc[4] += v * wr[4];
  }
#pragma unroll
  for (int c = 0; c < 5; ++c) {
    float r = warp_reduce_sum(acc[c]);
    if ((tid & 63) == 0) sacc[c][tid >> 6] = r;
  }
  __syncthreads();
  if (tid < 5)
    out[p * 5 + tid] = sacc[tid][0] + sacc[tid][1] + sacc[tid][2] + sacc[tid][3] + bc[tid];
}

// ---------------- host orchestration ----------------
extern "C" void kernel_launch(void* const* d_in, const int* in_sizes, int n_in,
                              void* d_out, int out_size, void* d_ws, size_t ws_size,
                              hipStream_t stream) {
  (void)in_sizes; (void)n_in; (void)out_size; (void)ws_size;
  const int* ids = (const int*)d_in[0];
  const float* masks = (const float*)d_in[1];
  const int* span_idx = (const int*)d_in[2];
  const int* mids = (const int*)d_in[3];
  const int* eom = (const int*)d_in[4];
  const int* htp = (const int*)d_in[5];
  const float* emb = (const float*)d_in[6];
  const float* pos = (const float*)d_in[7];
  const float* ln_emb_g = (const float*)d_in[8];
  const float* ln_emb_b = (const float*)d_in[9];
  const float* Wq = (const float*)d_in[10];
  const float* Wk = (const float*)d_in[11];
  const float* Wv = (const float*)d_in[12];
  const float* Wo = (const float*)d_in[13];
  const float* bq = (const float*)d_in[14];
  const float* bk = (const float*)d_in[15];
  const float* bv = (const float*)d_in[16];
  const float* bo = (const float*)d_in[17];
  const float* ln1_g = (const float*)d_in[18];
  const float* ln1_b = (const float*)d_in[19];
  const float* Wff1 = (const float*)d_in[20];
  const float* bff1 = (const float*)d_in[21];
  const float* Wff2 = (const float*)d_in[22];
  const float* bff2 = (const float*)d_in[23];
  const float* ln2_g = (const float*)d_in[24];
  const float* ln2_b = (const float*)d_in[25];
  const float* c1w = (const float*)d_in[26];
  const float* c1b = (const float*)d_in[27];
  const float* c2w = (const float*)d_in[28];
  const float* c2b = (const float*)d_in[29];
  const float* Wbil = (const float*)d_in[30];
  const float* bbil = (const float*)d_in[31];
  const float* Wue = (const float*)d_in[32];
  const float* bue = (const float*)d_in[33];
  const float* Wcls = (const float*)d_in[34];
  const float* bcls = (const float*)d_in[35];
  float* out = (float*)d_out;

  // ---- workspace carve (total 62.13 MB < 62.9 MB proven-working bound) ----
  char* base = (char*)d_ws;
  size_t off = 0;
  float* x = (float*)(base + off);       off += (size_t)NT * D * 4;   // 7.86 MB
  float* entbase = (float*)(base + off); off += 6u * 1024 * 1024;     // 6 MB
  ushortT* xb   = (ushortT*)(base + off); off += (size_t)NT * D * 2;  // 3.93 MB
  ushortT* qb   = (ushortT*)(base + off); off += (size_t)NT * D * 2;
  ushortT* kb   = (ushortT*)(base + off); off += (size_t)NT * D * 2;
  ushortT* vb   = (ushortT*)(base + off); off += (size_t)NT * D * 2;
  ushortT* ctxb = (ushortT*)(base + off); off += (size_t)NT * D * 2;
  ushortT* WTbuf = (ushortT*)(base + off); off += (size_t)D * FFD * 2; // 4.72 MB (max weight)
  char* bigc = base + off;  // 23,592,960 B shared, phase-disjoint:
  //  FFN phase : tmp f32 [0, 7.86MB) + ffb bf16 [7.86, 23.6MB)
  //  attn phase: scb bf16 [7.86, 14.16MB) + vtb bf16 [14.16, 14.95MB)  (tmp slot free)
  //  tail phase: h1 [0, 14.75MB) + w2t [14.75, 17.1MB) + ht1 [17.1, 17.2MB)
  float* tmp = (float*)bigc;
  ushortT* ffb = (ushortT*)(bigc + 7864320);
  ushortT* scb = (ushortT*)(bigc + 7864320);
  ushortT* vtb = (ushortT*)(bigc + 7864320 + 6291456);
  float* h1 = (float*)bigc;
  float* w2t = (float*)(bigc + 14745600);
  float* ht1 = (float*)(bigc + 17104896);

  // entity region layout (usage ~5.6 MB of the 6 MB reserve)
  float* m_sum = entbase;
  float* m_cnt = m_sum + (size_t)M_N * D;
  float* e_sum = m_cnt + M_N;
  float* e_cnt = e_sum + (size_t)E_N * D;
  int* last_m = (int*)(e_cnt + E_N);
  float* ent = (float*)(last_m + E_N);
  float* ep = ent + (size_t)E_N * D;
  float* epw = ep + (size_t)EPAD * D;
  float* norms = epw + (size_t)EPAD * D;
  float* attn_in = norms + EPAD;
  float* ht0 = attn_in + 3 * NPIX;
  float* hsb = ht0 + (size_t)P_N * C1;
  float* tsb = hsb + (size_t)P_N * 832;

  embed_ln_kernel<<<NT, 256, 0, stream>>>(ids, emb, pos, ln_emb_g, ln_emb_b, x, xb);

  const size_t WDD = (size_t)D * D;
  for (int l = 0; l < LNUM; ++l) {
    // Q, K, V projections — JIT weight transpose into the single WTbuf
    wcvt_t_kernel<<<dim3(D / 32, D / 32), 256, 0, stream>>>(Wq + l * WDD, WTbuf, D, D);
    gemm_bf16<<<dim3(D / 128, NT / 128), 256, 0, stream>>>(xb, D, WTbuf, D, nullptr, qb, D, D, bq + l * D, 0);
    wcvt_t_kernel<<<dim3(D / 32, D / 32), 256, 0, stream>>>(Wk + l * WDD, WTbuf, D, D);
    gemm_bf16<<<dim3(D / 128, NT / 128), 256, 0, stream>>>(xb, D, WTbuf, D, nullptr, kb, D, D, bk + l * D, 0);
    wcvt_t_kernel<<<dim3(D / 32, D / 32), 256, 0, stream>>>(Wv + l * WDD, WTbuf, D, D);
    gemm_bf16<<<dim3(D / 128, NT / 128), 256, 0, stream>>>(xb, D, WTbuf, D, nullptr, vb, D, D, bv + l * D, 0);

    // attention, one sequence at a time (scb/vtb fit in the shared big region)
    for (int b = 0; b < NSEQ; ++b) {
      vt_kernel<<<dim3(2, 16, H), 256, 0, stream>>>(vb, vtb, b);
      attn_scores_mfma<<<dim3(4, 4, H), 256, 0, stream>>>(qb, kb, masks, scb, b);
      attn_softmax_bf16<<<H * S, 256, 0, stream>>>(scb);
      attn_pv_mfma<<<dim3(4, H), 256, 0, stream>>>(scb, vtb, ctxb, b);
    }

    // output projection + LN
    wcvt_t_kernel<<<dim3(D / 32, D / 32), 256, 0, stream>>>(Wo + l * WDD, WTbuf, D, D);
    gemm_bf16<<<dim3(D / 128, NT / 128), 256, 0, stream>>>(ctxb, D, WTbuf, D, tmp, nullptr, D, D, bo + l * D, 0);
    add_ln_kernel<<<NT, 256, 0, stream>>>(x, tmp, ln1_g + l * D, ln1_b + l * D, xb);

    // FFN
    wcvt_t_kernel<<<dim3(FFD / 32, D / 32), 256, 0, stream>>>(Wff1 + (size_t)l * D * FFD, WTbuf, D, FFD);
    gemm_bf16<<<dim3(FFD / 128, NT / 128), 256, 0, stream>>>(xb, D, WTbuf, D, nullptr, ffb, FFD, D, bff1 + (size_t)l * FFD, 1);
    wcvt_t_kernel<<<dim3(D / 32, FFD / 32), 256, 0, stream>>>(Wff2 + (size_t)l * FFD * D, WTbuf, FFD, D);
    gemm_bf16<<<dim3(D / 128, NT / 128), 256, 0, stream>>>(ffb, FFD, WTbuf, FFD, tmp, nullptr, D, FFD, bff2 + l * D, 0);
    add_ln_kernel<<<NT, 256, 0, stream>>>(x, tmp, ln2_g + l * D, ln2_b + l * D, xb);
  }

  // zero atomic accumulators + ep padding
  size_t zero_bytes = (size_t)((char*)(ep + (size_t)EPAD * D) - (char*)m_sum);
  hipMemsetAsync(m_sum, 0, zero_bytes, stream);

  seg_mention_kernel<<<T_N, 256, 0, stream>>>(x, span_idx, mids, m_sum, m_cnt);
  m_div_kernel<<<(M_N * D + 255) / 256, 256, 0, stream>>>(m_sum, m_cnt);
  seg_entity_kernel<<<M_N, 256, 0, stream>>>(m_sum, eom, e_sum, e_cnt, last_m);
  ent_make_kernel<<<E_N, 256, 0, stream>>>(e_sum, e_cnt, last_m, m_sum, ent, ep);
  row_norms_kernel<<<EPAD, 256, 0, stream>>>(ep, norms);
  gemm_f32<<<dim3((D + 63) / 64, (EPAD + 63) / 64), 256, 0, stream>>>(ep, D, Wbil, D, epw, D, EPAD, D, D, nullptr, 0);
  pair_maps_kernel<<<NPIX / 4, 256, 0, stream>>>(ep, epw, norms, bbil, attn_in);
  conv1_kernel<<<dim3((NPIX + 255) / 256, C1), 256, 0, stream>>>(attn_in, c1w, c1b, h1);
  w2t_kernel<<<dim3(2304 / 32, C1 / 32), 256, 0, stream>>>(c2w, w2t);
  pair_conv2_kernel<<<P_N, 256, 0, stream>>>(h1, w2t, c2b, htp, ht0);
  gemm_f32<<<dim3(1, (P_N + 63) / 64), 256, 0, stream>>>(ht0, C1, Wue, 64, ht1, 64, P_N, 64, C1, bue, 0);
  pair_feats_kernel<<<P_N, 256, 0, stream>>>(ent, htp, ht1, hsb, tsb);
  final_kernel<<<P_N, 256, 0, stream>>>(hsb, tsb, Wcls, bcls, out);
}